// Round 13
// baseline (360.945 us; speedup 1.0000x reference)
//
#include <hip/hip_runtime.h>

struct CgPtrs { const float* p[9]; };               // p[l1*3+l2]
struct Desc  { int s00, s01, s10, s11, Ereg, E; };

__host__ __device__ constexpr int DSL(int s){ return s<2?1:(s==2?3:5); }   // 2l+1 of slot
__host__ __device__ constexpr int PRE(int s){ return s==0?0:(s==1?1:(s==2?2:5)); }
__host__ __device__ constexpr int LSL(int s){ return s<2?0:(s==2?1:2); }
__host__ __device__ constexpr int OFT(int a,int b){ return PRE(a)*10 + DSL(a)*PRE(b); }

// ---- kernel 1: per-edge (rank,class) into ws; g2b floats into out tail ----
__global__ __launch_bounds__(256) void prep_kernel(
    const int* __restrict__ sel00, const int* __restrict__ sel01,
    const int* __restrict__ sel10, const int* __restrict__ sel11,
    Desc d, int* __restrict__ rank, float* __restrict__ og)
{
    int u = blockIdx.x*256 + threadIdx.x;
    if (u < d.s00){ int e=sel00[u]; rank[e]=(u<<2)|0; og[e]=(float)u; return; } u-=d.s00;
    if (u < d.s01){ int e=sel01[u]; rank[e]=(u<<2)|1; og[e]=(float)u; return; } u-=d.s01;
    if (u < d.s10){ int e=sel10[u]; rank[e]=(u<<2)|2; og[e]=(float)u; return; } u-=d.s10;
    if (u < d.s11){ int e=sel11[u]; rank[e]=(u<<2)|3; og[e]=(float)u; return; }
}

// A-piece: C1[AB+j] += sum_k x[OFT(S1,S2)+k] * cgA[(I0*d2+j)*K+k]
template<int S1,int S2,int I0,int AB>
__device__ __forceinline__ void pA(const float* __restrict__ x, const CgPtrs& cg, float* acc){
    constexpr int d1=DSL(S1), d2=DSL(S2), K=d1*d2, xo=OFT(S1,S2);
    const float* __restrict__ w = cg.p[LSL(S1)*3+LSL(S2)];
    float xc[K];
    #pragma unroll
    for (int k=0;k<K;++k) xc[k]=x[xo+k];
    #pragma unroll
    for (int j=0;j<d2;++j){
        float a=acc[AB+j];
        #pragma unroll
        for (int k=0;k<K;++k) a=fmaf(xc[k], w[(I0*d2+j)*K+k], a);
        acc[AB+j]=a;
    }
}
// T-piece: T[AB+j] += sum_k x[OFT(S2,S1)+k] * cgB[(j*d1+I0)*K+k]  (partner's y-term)
template<int S1,int S2,int I0,int AB>
__device__ __forceinline__ void pT(const float* __restrict__ x, const CgPtrs& cg, float* acc){
    constexpr int d1=DSL(S1), d2=DSL(S2), K=d1*d2, xo=OFT(S2,S1);
    const float* __restrict__ w = cg.p[LSL(S2)*3+LSL(S1)];
    float xc[K];
    #pragma unroll
    for (int k=0;k<K;++k) xc[k]=x[xo+k];
    #pragma unroll
    for (int j=0;j<d2;++j){
        float a=acc[AB+j];
        #pragma unroll
        for (int k=0;k<K;++k) a=fmaf(xc[k], w[(j*d1+I0)*K+k], a);
        acc[AB+j]=a;
    }
}

template<int S1,int I0,int AB>
__device__ __forceinline__ void rowfullA(const float* x, const CgPtrs& cg, float* a){
    pA<S1,0,I0,AB+0>(x,cg,a); pA<S1,1,I0,AB+1>(x,cg,a);
    pA<S1,2,I0,AB+2>(x,cg,a); pA<S1,3,I0,AB+5>(x,cg,a);
}
template<int S1,int I0,int AB>
__device__ __forceinline__ void rowfullT(const float* x, const CgPtrs& cg, float* a){
    pT<S1,0,I0,AB+0>(x,cg,a); pT<S1,1,I0,AB+1>(x,cg,a);
    pT<S1,2,I0,AB+2>(x,cg,a); pT<S1,3,I0,AB+5>(x,cg,a);
}
template<int S1,int I0,int AB>
__device__ __forceinline__ void rowrestA(const float* x, const CgPtrs& cg, float* a){
    pA<S1,0,I0,AB+0>(x,cg,a); pA<S1,1,I0,AB+1>(x,cg,a); pA<S1,2,I0,AB+2>(x,cg,a);
}
template<int S1,int I0,int AB>
__device__ __forceinline__ void rowrestT(const float* x, const CgPtrs& cg, float* a){
    pT<S1,0,I0,AB+0>(x,cg,a); pT<S1,1,I0,AB+1>(x,cg,a); pT<S1,2,I0,AB+2>(x,cg,a);
}

// aligned store helpers (offsets compile-time-checked: odd starts, even starts, 16B-aligned)
__device__ __forceinline__ void st5o(float* p, const float* a){   // odd float offset
    p[0]=a[0]; *(float2*)(p+1)=make_float2(a[1],a[2]); *(float2*)(p+3)=make_float2(a[3],a[4]);
}
__device__ __forceinline__ void st5e(float* p, const float* a){   // even float offset
    *(float2*)(p)=make_float2(a[0],a[1]); *(float2*)(p+2)=make_float2(a[2],a[3]); p[4]=a[4];
}
__device__ __forceinline__ void st10f(float* p, const float* a){  // even float offset
    #pragma unroll
    for (int j=0;j<5;++j) *(float2*)(p+2*j)=make_float2(a[2*j],a[2*j+1]);
}
__device__ __forceinline__ void st4p(float* p, const float* a){   // 16B-aligned, packed cols {0,2,3,4}
    *(float4*)p = make_float4(a[0],a[2],a[3],a[4]);
}

// group G: compute C1+T pieces, combine via pair-shuffle, store per class
template<int G>
__device__ __forceinline__ void do_group(
    const float* x, bool slf, bool act, int rk, int c, const CgPtrs& cg,
    float* __restrict__ o00, float* __restrict__ o01,
    float* __restrict__ o10, float* __restrict__ o11)
{
    float c1[15], tt[15];
    #pragma unroll
    for (int u=0;u<15;++u){ c1[u]=0.f; tt[u]=0.f; }

    if constexpr (G==0){ pA<3,3,0,0>(x,cg,c1); rowfullA<0,0,5>(x,cg,c1);
                         pT<3,3,0,0>(x,cg,tt); rowfullT<0,0,5>(x,cg,tt); }
    if constexpr (G==1){ pA<3,3,1,0>(x,cg,c1); rowfullA<1,0,5>(x,cg,c1);
                         pT<3,3,1,0>(x,cg,tt); rowfullT<1,0,5>(x,cg,tt); }
    if constexpr (G==2){ pA<3,3,2,0>(x,cg,c1); rowrestA<3,3,5>(x,cg,c1);
                         pT<3,3,2,0>(x,cg,tt); rowrestT<3,3,5>(x,cg,tt); }
    if constexpr (G==3){ pA<3,3,3,0>(x,cg,c1); rowrestA<3,4,5>(x,cg,c1);
                         pT<3,3,3,0>(x,cg,tt); rowrestT<3,4,5>(x,cg,tt); }
    if constexpr (G==4){ pA<3,3,4,0>(x,cg,c1);
                         pT<3,3,4,0>(x,cg,tt); }
    if constexpr (G==5){ rowfullA<2,0,0>(x,cg,c1); rowrestA<3,0,10>(x,cg,c1);
                         rowfullT<2,0,0>(x,cg,tt); rowrestT<3,0,10>(x,cg,tt); }
    if constexpr (G==6){ rowfullA<2,1,0>(x,cg,c1); rowrestA<3,1,10>(x,cg,c1);
                         rowfullT<2,1,0>(x,cg,tt); rowrestT<3,1,10>(x,cg,tt); }
    if constexpr (G==7){ rowfullA<2,2,0>(x,cg,c1); rowrestA<3,2,10>(x,cg,c1);
                         rowfullT<2,2,0>(x,cg,tt); rowrestT<3,2,10>(x,cg,tt); }

    constexpr int NA = (G==2||G==3)?10:((G==4)?5:15);
    float acc[15];
    #pragma unroll
    for (int u=0;u<NA;++u){
        float tv = __shfl_xor(tt[u],1);             // partner's y-term (inv(e)=e^1)
        acc[u] = c1[u] + (slf ? tt[u] : tv);        // self edges: y == x
    }
    if (!act) return;

    if constexpr (G==0){
        if (c==3){ float* o=o11+(size_t)rk*100; st5o(o+55,acc); st10f(o+0,acc+5); }
        else if (c==2){ st4p(o10+(size_t)rk*40+0,  acc+5); }
        else if (c==1){ st10f(o01+(size_t)rk*40+0, acc+5); }
        else          { st4p(o00+(size_t)rk*16+0,  acc+5); }
    }
    if constexpr (G==1){
        if (c==3){ float* o=o11+(size_t)rk*100; st5o(o+65,acc); st10f(o+10,acc+5); }
        else if (c==2){ st4p(o10+(size_t)rk*40+4, acc+5); }
    }
    if constexpr (G==2){
        if (c==3){ float* o=o11+(size_t)rk*100; st5o(o+75,acc); st5e(o+80,acc+5); }
        else if (c==2){ st4p(o10+(size_t)rk*40+32, acc+5); }
    }
    if constexpr (G==3){
        if (c==3){ float* o=o11+(size_t)rk*100; st5o(o+85,acc); st5e(o+90,acc+5); }
        else if (c==2){ st4p(o10+(size_t)rk*40+36, acc+5); }
    }
    if constexpr (G==4){
        if (c==3){ st5o(o11+(size_t)rk*100+95, acc); }
    }
    if constexpr (G==5){
        if (c==3){ float* o=o11+(size_t)rk*100; st10f(o+20,acc); st5e(o+50,acc+10); }
        else if (c==2){ st4p(o10+(size_t)rk*40+8, acc); st4p(o10+(size_t)rk*40+20, acc+10); }
        else if (c==1){ st10f(o01+(size_t)rk*40+10, acc); }
        else          { st4p(o00+(size_t)rk*16+4, acc); }
    }
    if constexpr (G==6){
        if (c==3){ float* o=o11+(size_t)rk*100; st10f(o+30,acc); st5e(o+60,acc+10); }
        else if (c==2){ st4p(o10+(size_t)rk*40+12, acc); st4p(o10+(size_t)rk*40+24, acc+10); }
        else if (c==1){ st10f(o01+(size_t)rk*40+20, acc); }
        else          { st4p(o00+(size_t)rk*16+8, acc); }
    }
    if constexpr (G==7){
        if (c==3){ float* o=o11+(size_t)rk*100; st10f(o+40,acc); st5e(o+70,acc+10); }
        else if (c==2){ st4p(o10+(size_t)rk*40+16, acc); st4p(o10+(size_t)rk*40+28, acc+10); }
        else if (c==1){ st10f(o01+(size_t)rk*40+30, acc); }
        else          { st4p(o00+(size_t)rk*16+12, acc); }
    }
}

// ---- kernel 2: block = 64 edges staged in LDS; 8 waves = 8 balanced row/col groups ----
__global__ __launch_bounds__(512,6) void ham_kernel(
    const float* __restrict__ fn, const float* __restrict__ fe,
    const int* __restrict__ rank,
    CgPtrs cg, Desc d, float* __restrict__ out)
{
    __shared__ float xs[64*101];
    float* o00 = out;
    float* o01 = o00 + (size_t)d.s00*16;
    float* o10 = o01 + (size_t)d.s01*40;
    float* o11 = o10 + (size_t)d.s10*40;

    const int e0  = blockIdx.x*64;
    const int tid = threadIdx.x;
    const int nE  = min(64, d.E - e0);

    // stage 0.5*fe' rows, float4 global loads (self-tail: fn[e-Ereg] fused)
    for (int idx = tid; idx < nE*25; idx += 512){
        const int row = idx/25, q = idx - 25*row;
        const int e = e0 + row;
        float4 v = *(const float4*)(fe + (size_t)e*100 + 4*q);
        if (e >= d.Ereg){
            float4 w = *(const float4*)(fn + (size_t)(e - d.Ereg)*100 + 4*q);
            v.x += w.x; v.y += w.y; v.z += w.z; v.w += w.w;
        }
        float* dst = xs + row*101 + 4*q;
        dst[0]=0.5f*v.x; dst[1]=0.5f*v.y; dst[2]=0.5f*v.z; dst[3]=0.5f*v.w;
    }
    __syncthreads();

    const int lane = tid & 63;
    const int grp  = tid >> 6;
    const int e = e0 + lane;
    const bool act = (lane < nE);
    const bool slf = (e >= d.Ereg);
    const int pk = act ? rank[e] : 0;
    const int rk = pk >> 2;
    const int c  = pk & 3;
    const float* x = xs + lane*101;

    if      (grp==0) do_group<0>(x,slf,act,rk,c,cg,o00,o01,o10,o11);
    else if (grp==1) do_group<1>(x,slf,act,rk,c,cg,o00,o01,o10,o11);
    else if (grp==2) do_group<2>(x,slf,act,rk,c,cg,o00,o01,o10,o11);
    else if (grp==3) do_group<3>(x,slf,act,rk,c,cg,o00,o01,o10,o11);
    else if (grp==4) do_group<4>(x,slf,act,rk,c,cg,o00,o01,o10,o11);
    else if (grp==5) do_group<5>(x,slf,act,rk,c,cg,o00,o01,o10,o11);
    else if (grp==6) do_group<6>(x,slf,act,rk,c,cg,o00,o01,o10,o11);
    else             do_group<7>(x,slf,act,rk,c,cg,o00,o01,o10,o11);
}

extern "C" void kernel_launch(void* const* d_in, const int* in_sizes, int n_in,
                              void* d_out, int out_size, void* d_ws, size_t ws_size,
                              hipStream_t stream)
{
    const float* fn  = (const float*)d_in[0];
    const float* fe  = (const float*)d_in[1];
    CgPtrs cg;
    for (int i = 0; i < 9; ++i) cg.p[i] = (const float*)d_in[6 + i];
    const int* sel00 = (const int*)d_in[15];
    const int* sel01 = (const int*)d_in[16];
    const int* sel10 = (const int*)d_in[17];
    const int* sel11 = (const int*)d_in[18];

    const int N = in_sizes[0] / 100;
    const int E = in_sizes[3] / 2;

    Desc d;
    d.s00 = in_sizes[15]; d.s01 = in_sizes[16]; d.s10 = in_sizes[17]; d.s11 = in_sizes[18];
    d.Ereg = E - N;
    d.E = E;

    float* out = (float*)d_out;
    float* og  = out + (size_t)d.s00*16 + (size_t)d.s01*40 + (size_t)d.s10*40 + (size_t)d.s11*100;
    int* rank = (int*)d_ws;              // E ints

    prep_kernel<<<(E + 255)/256, 256, 0, stream>>>(sel00, sel01, sel10, sel11, d, rank, og);
    ham_kernel <<<(E + 63)/64,   512, 0, stream>>>(fn, fe, rank, cg, d, out);
}

// Round 14
// 128.200 us; speedup vs baseline: 2.8155x; 2.8155x over previous
//
#include <hip/hip_runtime.h>

struct CgPtrs { const float* p[9]; };               // p[l1*3+l2]
struct Desc  { int s00, s01, s10, s11, Ereg, E; };

__host__ __device__ constexpr int DSL(int s){ return s<2?1:(s==2?3:5); }   // 2l+1 of slot
__host__ __device__ constexpr int PRE(int s){ return s==0?0:(s==1?1:(s==2?2:5)); }
__host__ __device__ constexpr int LSL(int s){ return s<2?0:(s==2?1:2); }
__host__ __device__ constexpr int OFT(int a,int b){ return PRE(a)*10 + DSL(a)*PRE(b); }

// ---- kernel 1: per-edge (rank,class) into ws ----
__global__ __launch_bounds__(256) void prep_kernel(
    const int* __restrict__ sel00, const int* __restrict__ sel01,
    const int* __restrict__ sel10, const int* __restrict__ sel11,
    Desc d, int* __restrict__ rank)
{
    int u = blockIdx.x*256 + threadIdx.x;
    if (u < d.s00){ int e=sel00[u]; rank[e]=(u<<2)|0; return; } u-=d.s00;
    if (u < d.s01){ int e=sel01[u]; rank[e]=(u<<2)|1; return; } u-=d.s01;
    if (u < d.s10){ int e=sel10[u]; rank[e]=(u<<2)|2; return; } u-=d.s10;
    if (u < d.s11){ int e=sel11[u]; rank[e]=(u<<2)|3; return; }
}

// rows i=I0..I0+NR-1 of band S1, one S2 column-chunk, into acc[NR][10]
template<int S1,int S2,int I0,int NR>
__device__ __forceinline__ void rows_chunk(const float* __restrict__ x,
    const float* __restrict__ y, const CgPtrs& cg, float* acc)
{
    constexpr int d1=DSL(S1), d2=DSL(S2), K=d1*d2;
    constexpr int xo=OFT(S1,S2), yo=OFT(S2,S1), c0=PRE(S2);
    const float* __restrict__ wA = cg.p[LSL(S1)*3+LSL(S2)];   // cg_{l1,l2}[i][j][k]
    const float* __restrict__ wB = cg.p[LSL(S2)*3+LSL(S1)];   // cg_{l2,l1}[j][i][k]
    float xc[K], yc[K];
    #pragma unroll
    for (int k=0;k<K;++k) xc[k]=x[xo+k];
    #pragma unroll
    for (int k=0;k<K;++k) yc[k]=y[yo+k];
    #pragma unroll
    for (int r=0;r<NR;++r){
        #pragma unroll
        for (int j=0;j<d2;++j){
            float a = acc[r*10 + c0 + j];
            #pragma unroll
            for (int k=0;k<K;++k) a = fmaf(xc[k], wA[((I0+r)*d2+j)*K+k], a);
            #pragma unroll
            for (int k=0;k<K;++k) a = fmaf(yc[k], wB[(j*d1+I0+r)*K+k], a);
            acc[r*10 + c0 + j] = a;
        }
    }
}

template<int S1,int I0,int NR>
__device__ __forceinline__ void band_all(const float* x, const float* y,
                                         const CgPtrs& cg, float* acc)
{
    rows_chunk<S1,0,I0,NR>(x,y,cg,acc);
    rows_chunk<S1,1,I0,NR>(x,y,cg,acc);
    rows_chunk<S1,2,I0,NR>(x,y,cg,acc);
    rows_chunk<S1,3,I0,NR>(x,y,cg,acc);
}

// packed-col float4 store for c0/c2 (cols {0,2,3,4} of a 10-wide acc row)
__device__ __forceinline__ void stcols(float* p, const float* ar){
    *(float4*)p = make_float4(ar[0], ar[2], ar[3], ar[4]);
}
// 10-float row store, offset known mod 4 at compile time
__device__ __forceinline__ void st10m0(float* p, const float* a){   // offset%4==0
    *(float4*)(p)   = make_float4(a[0],a[1],a[2],a[3]);
    *(float4*)(p+4) = make_float4(a[4],a[5],a[6],a[7]);
    *(float2*)(p+8) = make_float2(a[8],a[9]);
}
__device__ __forceinline__ void st10m2(float* p, const float* a){   // offset%4==2
    *(float2*)(p)   = make_float2(a[0],a[1]);
    *(float4*)(p+2) = make_float4(a[2],a[3],a[4],a[5]);
    *(float4*)(p+6) = make_float4(a[6],a[7],a[8],a[9]);
}

// ---- kernel 2: block = 64 edges staged in LDS; wave = balanced row-group ----
__global__ __launch_bounds__(256,6) void ham_kernel(
    const float* __restrict__ fn, const float* __restrict__ fe,
    const int* __restrict__ rank,
    CgPtrs cg, Desc d, float* __restrict__ out, float* __restrict__ og)
{
    __shared__ float xs[64*101];
    float* o00 = out;
    float* o01 = o00 + (size_t)d.s00*16;
    float* o10 = o01 + (size_t)d.s01*40;
    float* o11 = o10 + (size_t)d.s10*40;

    const int e0  = blockIdx.x*64;
    const int tid = threadIdx.x;
    const int nE  = min(64, d.E - e0);

    // stage 0.5*fe' rows, float4 global loads (self-tail: fn[e-Ereg] fused)
    for (int idx = tid; idx < nE*25; idx += 256){
        const int row = idx/25, q = idx - 25*row;
        const int e = e0 + row;
        float4 v = *(const float4*)(fe + (size_t)e*100 + 4*q);
        if (e >= d.Ereg){
            float4 w = *(const float4*)(fn + (size_t)(e - d.Ereg)*100 + 4*q);
            v.x += w.x; v.y += w.y; v.z += w.z; v.w += w.w;
        }
        float* dst = xs + row*101 + 4*q;
        dst[0]=0.5f*v.x; dst[1]=0.5f*v.y; dst[2]=0.5f*v.z; dst[3]=0.5f*v.w;
    }
    __syncthreads();

    const int lane = tid & 63;
    const int grp  = ((tid>>6) + blockIdx.x) & 3;      // rotate groups across blocks
    const int e = e0 + lane;
    const bool act = (lane < nE);
    float acc[40];
    #pragma unroll
    for (int i=0;i<40;++i) acc[i]=0.f;

    int rk=0, c=0;
    if (act){
        const int pk = rank[e];
        rk = pk >> 2; c = pk & 3;
        if (grp == 0) og[e] = (float)rk;               // g2b, coalesced stream
        const float* x = xs + lane*101;
        const float* y = (e >= d.Ereg) ? x : xs + (lane^1)*101;  // inv(e)=e^1; self: y=x
        if      (grp==0){ band_all<0,0,1>(x,y,cg,acc);      // 10-rows 0,1,2,3
                          band_all<1,0,1>(x,y,cg,acc+10);
                          band_all<2,0,2>(x,y,cg,acc+20); }
        else if (grp==1){ band_all<2,2,1>(x,y,cg,acc);      // 10-rows 4,9
                          band_all<3,4,1>(x,y,cg,acc+10); }
        else if (grp==2){ band_all<3,0,2>(x,y,cg,acc); }    // 10-rows 5,6
        else            { band_all<3,2,2>(x,y,cg,acc); }    // 10-rows 7,8
    }

    if (act){
        if (grp==0){
            if (c==3){ float* o=o11+(size_t)rk*100;          // rows 0-3 contiguous, 40 floats
                #pragma unroll
                for (int u=0;u<10;++u)
                    *(float4*)(o+4*u) = make_float4(acc[4*u],acc[4*u+1],acc[4*u+2],acc[4*u+3]); }
            else if (c==2){ float* o=o10+(size_t)rk*40;
                stcols(o+0,acc); stcols(o+4,acc+10); stcols(o+8,acc+20); stcols(o+12,acc+30); }
            else if (c==1){ float* o=o01+(size_t)rk*40;      // 10-rows {0,2,3} -> packed 0,1,2
                st10m0(o+0,acc); st10m2(o+10,acc+20); st10m0(o+20,acc+30); }
            else { float* o=o00+(size_t)rk*16;
                stcols(o+0,acc); stcols(o+4,acc+20); stcols(o+8,acc+30); }
        } else if (grp==1){                                  // acc rows: 0 -> 10-row4, 1 -> 10-row9
            if (c==3){ float* o=o11+(size_t)rk*100;
                st10m0(o+40,acc); st10m2(o+90,acc+10); }
            else if (c==2){ float* o=o10+(size_t)rk*40;
                stcols(o+16,acc); stcols(o+36,acc+10); }
            else if (c==1){ float* o=o01+(size_t)rk*40;      // 10-row 4 -> packed row 3
                st10m2(o+30,acc); }
            else { float* o=o00+(size_t)rk*16; stcols(o+12,acc); }
        } else if (grp==2){                                  // 10-rows 5,6
            if (c==3){ float* o=o11+(size_t)rk*100;
                st10m2(o+50,acc); st10m0(o+60,acc+10); }
            else if (c==2){ float* o=o10+(size_t)rk*40;
                stcols(o+20,acc); stcols(o+24,acc+10); }
        } else {                                             // 10-rows 7,8
            if (c==3){ float* o=o11+(size_t)rk*100;
                st10m2(o+70,acc); st10m0(o+80,acc+10); }
            else if (c==2){ float* o=o10+(size_t)rk*40;
                stcols(o+28,acc); stcols(o+32,acc+10); }
        }
    }
}

extern "C" void kernel_launch(void* const* d_in, const int* in_sizes, int n_in,
                              void* d_out, int out_size, void* d_ws, size_t ws_size,
                              hipStream_t stream)
{
    const float* fn  = (const float*)d_in[0];
    const float* fe  = (const float*)d_in[1];
    CgPtrs cg;
    for (int i = 0; i < 9; ++i) cg.p[i] = (const float*)d_in[6 + i];
    const int* sel00 = (const int*)d_in[15];
    const int* sel01 = (const int*)d_in[16];
    const int* sel10 = (const int*)d_in[17];
    const int* sel11 = (const int*)d_in[18];

    const int N = in_sizes[0] / 100;
    const int E = in_sizes[3] / 2;

    Desc d;
    d.s00 = in_sizes[15]; d.s01 = in_sizes[16]; d.s10 = in_sizes[17]; d.s11 = in_sizes[18];
    d.Ereg = E - N;
    d.E = E;

    float* out = (float*)d_out;
    float* og  = out + (size_t)d.s00*16 + (size_t)d.s01*40 + (size_t)d.s10*40 + (size_t)d.s11*100;
    int* rank = (int*)d_ws;              // E ints

    prep_kernel<<<(E + 255)/256, 256, 0, stream>>>(sel00, sel01, sel10, sel11, d, rank);
    ham_kernel <<<(E + 63)/64,   256, 0, stream>>>(fn, fe, rank, cg, d, out, og);
}

// Round 15
// 112.043 us; speedup vs baseline: 3.2215x; 1.1442x over previous
//
#include <hip/hip_runtime.h>

struct CgPtrs { const float* p[9]; };               // p[l1*3+l2]
struct Desc  { int s00, s01, s10, s11, Ereg, E; };

__host__ __device__ constexpr int DSL(int s){ return s<2?1:(s==2?3:5); }   // 2l+1 of slot
__host__ __device__ constexpr int PRE(int s){ return s==0?0:(s==1?1:(s==2?2:5)); }
__host__ __device__ constexpr int LSL(int s){ return s<2?0:(s==2?1:2); }
__host__ __device__ constexpr int OFT(int a,int b){ return PRE(a)*10 + DSL(a)*PRE(b); }

// ---- kernel 1: per-edge (rank,class) into ws; g2b floats into out tail ----
__global__ __launch_bounds__(256) void prep_kernel(
    const int* __restrict__ sel00, const int* __restrict__ sel01,
    const int* __restrict__ sel10, const int* __restrict__ sel11,
    Desc d, int* __restrict__ rank, float* __restrict__ og)
{
    int u = blockIdx.x*256 + threadIdx.x;
    if (u < d.s00){ int e=sel00[u]; rank[e]=(u<<2)|0; og[e]=(float)u; return; } u-=d.s00;
    if (u < d.s01){ int e=sel01[u]; rank[e]=(u<<2)|1; og[e]=(float)u; return; } u-=d.s01;
    if (u < d.s10){ int e=sel10[u]; rank[e]=(u<<2)|2; og[e]=(float)u; return; } u-=d.s10;
    if (u < d.s11){ int e=sel11[u]; rank[e]=(u<<2)|3; og[e]=(float)u; return; }
}

// rows i=I0..I0+NR-1 of band S1, one S2 column-chunk, into acc[NR][10]
template<int S1,int S2,int I0,int NR>
__device__ __forceinline__ void rows_chunk(const float* __restrict__ x,
    const float* __restrict__ y, const CgPtrs& cg, float* acc)
{
    constexpr int d1=DSL(S1), d2=DSL(S2), K=d1*d2;
    constexpr int xo=OFT(S1,S2), yo=OFT(S2,S1), c0=PRE(S2);
    const float* __restrict__ wA = cg.p[LSL(S1)*3+LSL(S2)];   // cg_{l1,l2}[i][j][k]
    const float* __restrict__ wB = cg.p[LSL(S2)*3+LSL(S1)];   // cg_{l2,l1}[j][i][k]
    float xc[K], yc[K];
    #pragma unroll
    for (int k=0;k<K;++k) xc[k]=x[xo+k];
    #pragma unroll
    for (int k=0;k<K;++k) yc[k]=y[yo+k];
    #pragma unroll
    for (int r=0;r<NR;++r){
        #pragma unroll
        for (int j=0;j<d2;++j){
            float a = acc[r*10 + c0 + j];
            #pragma unroll
            for (int k=0;k<K;++k) a = fmaf(xc[k], wA[((I0+r)*d2+j)*K+k], a);
            #pragma unroll
            for (int k=0;k<K;++k) a = fmaf(yc[k], wB[(j*d1+I0+r)*K+k], a);
            acc[r*10 + c0 + j] = a;
        }
    }
}

template<int S1,int I0,int NR>
__device__ __forceinline__ void band_all(const float* x, const float* y,
                                         const CgPtrs& cg, float* acc)
{
    rows_chunk<S1,0,I0,NR>(x,y,cg,acc);
    rows_chunk<S1,1,I0,NR>(x,y,cg,acc);
    rows_chunk<S1,2,I0,NR>(x,y,cg,acc);
    rows_chunk<S1,3,I0,NR>(x,y,cg,acc);
}

// packed-col float4 store for c0/c2 (cols {0,2,3,4} of a 10-wide acc row)
__device__ __forceinline__ void stcols(float* p, const float* ar){
    *(float4*)p = make_float4(ar[0], ar[2], ar[3], ar[4]);
}
__device__ __forceinline__ void strow10(float* p, const float* ar){
    #pragma unroll
    for (int j=0;j<5;++j) *(float2*)(p+2*j) = make_float2(ar[2*j], ar[2*j+1]);
}

// ---- kernel 2: block = 64 edges staged in LDS; wave = balanced row-group ----
__global__ __launch_bounds__(256,6) void ham_kernel(
    const float* __restrict__ fn, const float* __restrict__ fe,
    const int* __restrict__ rank,
    CgPtrs cg, Desc d, float* __restrict__ out)
{
    __shared__ float xs[64*101];
    float* o00 = out;
    float* o01 = o00 + (size_t)d.s00*16;
    float* o10 = o01 + (size_t)d.s01*40;
    float* o11 = o10 + (size_t)d.s10*40;

    const int e0  = blockIdx.x*64;
    const int tid = threadIdx.x;
    const int nE  = min(64, d.E - e0);

    // stage 0.5*fe' rows, float4 global loads (self-tail: fn[e-Ereg] fused)
    for (int idx = tid; idx < nE*25; idx += 256){
        const int row = idx/25, q = idx - 25*row;
        const int e = e0 + row;
        float4 v = *(const float4*)(fe + (size_t)e*100 + 4*q);
        if (e >= d.Ereg){
            float4 w = *(const float4*)(fn + (size_t)(e - d.Ereg)*100 + 4*q);
            v.x += w.x; v.y += w.y; v.z += w.z; v.w += w.w;
        }
        float* dst = xs + row*101 + 4*q;
        dst[0]=0.5f*v.x; dst[1]=0.5f*v.y; dst[2]=0.5f*v.z; dst[3]=0.5f*v.w;
    }
    __syncthreads();

    const int lane = tid & 63;
    const int grp  = ((tid>>6) + blockIdx.x) & 3;      // rotate groups across blocks
    const int e = e0 + lane;
    const bool act = (lane < nE);
    float acc[40];
    #pragma unroll
    for (int i=0;i<40;++i) acc[i]=0.f;

    int rk=0, c=0;
    if (act){
        const int pk = rank[e];
        rk = pk >> 2; c = pk & 3;
        const float* x = xs + lane*101;
        const float* y = (e >= d.Ereg) ? x : xs + (lane^1)*101;  // inv(e)=e^1; self: y=x
        if      (grp==0){ band_all<0,0,1>(x,y,cg,acc);      // 10-rows 0,1,2,3
                          band_all<1,0,1>(x,y,cg,acc+10);
                          band_all<2,0,2>(x,y,cg,acc+20); }
        else if (grp==1){ band_all<2,2,1>(x,y,cg,acc);      // 10-rows 4,9
                          band_all<3,4,1>(x,y,cg,acc+10); }
        else if (grp==2){ band_all<3,0,2>(x,y,cg,acc); }    // 10-rows 5,6
        else            { band_all<3,2,2>(x,y,cg,acc); }    // 10-rows 7,8
    }

    if (act){
        if (grp==0){
            if (c==3){ float* o=o11+(size_t)rk*100;
                #pragma unroll
                for (int u=0;u<10;++u)
                    *(float4*)(o+4*u) = make_float4(acc[4*u],acc[4*u+1],acc[4*u+2],acc[4*u+3]); }
            else if (c==2){ float* o=o10+(size_t)rk*40;
                stcols(o+0,acc); stcols(o+4,acc+10); stcols(o+8,acc+20); stcols(o+12,acc+30); }
            else if (c==1){ float* o=o01+(size_t)rk*40;     // 10-rows {0,2,3} -> packed 0,1,2
                strow10(o+0,acc); strow10(o+10,acc+20); strow10(o+20,acc+30); }
            else { float* o=o00+(size_t)rk*16;
                stcols(o+0,acc); stcols(o+4,acc+20); stcols(o+8,acc+30); }
        } else if (grp==1){                                  // acc rows: 0 -> 10-row4, 1 -> 10-row9
            if (c==3){ float* o=o11+(size_t)rk*100;
                strow10(o+40,acc); strow10(o+90,acc+10); }
            else if (c==2){ float* o=o10+(size_t)rk*40;
                stcols(o+16,acc); stcols(o+36,acc+10); }
            else if (c==1){ float* o=o01+(size_t)rk*40;     // 10-row 4 -> packed row 3
                strow10(o+30,acc); }
            else { float* o=o00+(size_t)rk*16; stcols(o+12,acc); }
        } else if (grp==2){                                  // 10-rows 5,6 (type1 rows only)
            if (c==3){ float* o=o11+(size_t)rk*100;
                strow10(o+50,acc); strow10(o+60,acc+10); }
            else if (c==2){ float* o=o10+(size_t)rk*40;
                stcols(o+20,acc); stcols(o+24,acc+10); }
        } else {                                             // 10-rows 7,8
            if (c==3){ float* o=o11+(size_t)rk*100;
                strow10(o+70,acc); strow10(o+80,acc+10); }
            else if (c==2){ float* o=o10+(size_t)rk*40;
                stcols(o+28,acc); stcols(o+32,acc+10); }
        }
    }
}

extern "C" void kernel_launch(void* const* d_in, const int* in_sizes, int n_in,
                              void* d_out, int out_size, void* d_ws, size_t ws_size,
                              hipStream_t stream)
{
    const float* fn  = (const float*)d_in[0];
    const float* fe  = (const float*)d_in[1];
    CgPtrs cg;
    for (int i = 0; i < 9; ++i) cg.p[i] = (const float*)d_in[6 + i];
    const int* sel00 = (const int*)d_in[15];
    const int* sel01 = (const int*)d_in[16];
    const int* sel10 = (const int*)d_in[17];
    const int* sel11 = (const int*)d_in[18];

    const int N = in_sizes[0] / 100;
    const int E = in_sizes[3] / 2;

    Desc d;
    d.s00 = in_sizes[15]; d.s01 = in_sizes[16]; d.s10 = in_sizes[17]; d.s11 = in_sizes[18];
    d.Ereg = E - N;
    d.E = E;

    float* out = (float*)d_out;
    float* og  = out + (size_t)d.s00*16 + (size_t)d.s01*40 + (size_t)d.s10*40 + (size_t)d.s11*100;
    int* rank = (int*)d_ws;              // E ints

    prep_kernel<<<(E + 255)/256, 256, 0, stream>>>(sel00, sel01, sel10, sel11, d, rank, og);
    ham_kernel <<<(E + 63)/64,   256, 0, stream>>>(fn, fe, rank, cg, d, out);
}